// Round 5
// baseline (386.278 us; speedup 1.0000x reference)
//
#include <hip/hip_runtime.h>
#include <hip/hip_bf16.h>

typedef __attribute__((ext_vector_type(8))) short bf16x8;
typedef __attribute__((ext_vector_type(4))) float f32x4;
typedef __attribute__((ext_vector_type(2))) float f32x2;

#define B_SZ   4096
#define K1     25
#define K2     10
#define M_L1   45056   /* B*(1+K2) */
#define D      256
#define K_DIM  512
#define N_NODES 200000

static __device__ __forceinline__ unsigned short f2bf(float f) {
    union { float f; unsigned u; } v; v.f = f;
    return (unsigned short)((v.u + 0x7fffu + ((v.u >> 16) & 1u)) >> 16);
}
static __device__ __forceinline__ float bf2f(unsigned short h) {
    union { unsigned u; float f; } v; v.u = ((unsigned)h) << 16;
    return v.f;
}

// ---- convert features fp32 -> fp8 e4m3 (51.2M elems), streaming ----
__global__ __launch_bounds__(256)
void convert_fp8(const float* __restrict__ f, unsigned* __restrict__ f8) {
    const size_t i = ((size_t)blockIdx.x * 256 + threadIdx.x) * 8;
    const float4 a = *(const float4*)(f + i);
    const float4 b = *(const float4*)(f + i + 4);
    unsigned u0 = 0, u1 = 0;
    u0 = __builtin_amdgcn_cvt_pk_fp8_f32(a.x, a.y, u0, false);
    u0 = __builtin_amdgcn_cvt_pk_fp8_f32(a.z, a.w, u0, true);
    u1 = __builtin_amdgcn_cvt_pk_fp8_f32(b.x, b.y, u1, false);
    u1 = __builtin_amdgcn_cvt_pk_fp8_f32(b.z, b.w, u1, true);
    uint2 r; r.x = u0; r.y = u1;
    *(uint2*)(f8 + (i >> 2)) = r;
}

// ---- convert W1/W2 fp32 -> bf16 (131072 elements each) ----
__global__ __launch_bounds__(256)
void convert_w(const float* __restrict__ W1, const float* __restrict__ W2,
               unsigned short* __restrict__ W1b, unsigned short* __restrict__ W2b) {
    const int i = blockIdx.x * 256 + threadIdx.x;
    W1b[i] = f2bf(W1[i]);
    W2b[i] = f2bf(W2[i]);
}

// ---- FUSED layer 1: gather+mean -> LDS A-tile -> GEMM+ReLU -> h1 ----
// grid (704), 256 thr (4 waves). Tile: 64 rows x N=256 (wave w covers cols w*64..+63).
// LDS: 64x512 bf16 A-tile (64 KB), XOR-swizzled 16B chunks: chunk c of row r at
// slot (c&56)|((c^r)&7) -> ds_read_b128 frag reads are 2-way (free, m136).
// B-frags read directly from W1b (256 KB, L2-resident; each block reads it once).
// ONE barrier total; K-loop has no staging barriers.
__global__ __launch_bounds__(256)
void fused_l1(const float* __restrict__ feat,
              const unsigned* __restrict__ f8,
              const int* __restrict__ nodes_batch,
              const int* __restrict__ neigh2,
              const int* __restrict__ neigh1,
              const unsigned short* __restrict__ W1b,
              unsigned short* __restrict__ h1) {
    __shared__ unsigned short At[64 * 512];   // 65536 B
    const int tid  = threadIdx.x;
    const int w    = tid >> 6, lane = tid & 63;
    const int quad = lane >> 4, l16 = lane & 15;
    const int row0 = blockIdx.x << 6;

    // ---- phase 1: wave w builds rows w*16 .. w*16+15 ----
    for (int t = 0; t < 16; ++t) {
        const int r = (w << 4) + t;
        const int m = row0 + r;
        const int self_node = (m < B_SZ) ? nodes_batch[m] : neigh2[m - B_SZ];
        const int* nb = neigh1 + (size_t)m * K1;
        int idxv = (lane < K1) ? nb[lane] : 0;
        const float4 s = *(const float4*)(feat + (size_t)self_node * D + (lane << 2));
        unsigned q[K1];
        #pragma unroll
        for (int j = 0; j < K1; ++j)
            q[j] = f8[(size_t)__shfl(idxv, j) * (D / 4) + lane];
        float a0 = 0.f, a1 = 0.f, a2 = 0.f, a3 = 0.f;
        #pragma unroll
        for (int j = 0; j < K1; ++j) {
            const f32x2 lo = __builtin_amdgcn_cvt_pk_f32_fp8(q[j], false);
            const f32x2 hi = __builtin_amdgcn_cvt_pk_f32_fp8(q[j], true);
            a0 += lo.x; a1 += lo.y; a2 += hi.x; a3 += hi.y;
        }
        const float inv = 1.0f / (float)K1;
        // self: cols 4*lane -> byte off lane*8 -> chunk lane>>1 (0..31)
        // agg : cols 256+4*lane -> chunk 32+(lane>>1)
        const int cs = lane >> 1;
        const int ca = 32 + cs;
        const int slotS = (cs & 56) | ((cs ^ r) & 7);
        const int slotA = (ca & 56) | ((ca ^ r) & 7);
        const int sub = (lane & 1) << 2;          // 0 or 4 elems within 16B chunk
        *(ushort4*)&At[r * 512 + slotS * 8 + sub] =
            make_ushort4(f2bf(s.x), f2bf(s.y), f2bf(s.z), f2bf(s.w));
        *(ushort4*)&At[r * 512 + slotA * 8 + sub] =
            make_ushort4(f2bf(a0 * inv), f2bf(a1 * inv), f2bf(a2 * inv), f2bf(a3 * inv));
    }
    __syncthreads();

    // ---- phase 2: wave w computes C[0..63, wn..wn+63], wn = w*64 ----
    const int wn = w << 6;
    f32x4 acc[4][4];
    #pragma unroll
    for (int i = 0; i < 4; ++i)
        #pragma unroll
        for (int j = 0; j < 4; ++j)
            acc[i][j] = (f32x4){0.f, 0.f, 0.f, 0.f};

    #pragma unroll 4
    for (int s = 0; s < 16; ++s) {
        bf16x8 bfr[4], af[4];
        #pragma unroll
        for (int ni = 0; ni < 4; ++ni)
            bfr[ni] = *(const bf16x8*)(W1b +
                (size_t)(wn + ni * 16 + l16) * K_DIM + s * 32 + quad * 8);
        #pragma unroll
        for (int mi = 0; mi < 4; ++mi) {
            const int rr = mi * 16 + l16;
            const int c = (s << 2) + quad;
            const int slot = (c & 56) | ((c ^ rr) & 7);
            af[mi] = *(const bf16x8*)&At[rr * 512 + slot * 8];
        }
        #pragma unroll
        for (int mi = 0; mi < 4; ++mi)
            #pragma unroll
            for (int ni = 0; ni < 4; ++ni)
                acc[mi][ni] = __builtin_amdgcn_mfma_f32_16x16x32_bf16(
                    af[mi], bfr[ni], acc[mi][ni], 0, 0, 0);
    }

    #pragma unroll
    for (int mi = 0; mi < 4; ++mi)
        #pragma unroll
        for (int ni = 0; ni < 4; ++ni)
            #pragma unroll
            for (int r = 0; r < 4; ++r) {
                const size_t gm = (size_t)row0 + mi * 16 + quad * 4 + r;
                const size_t gn = wn + ni * 16 + l16;
                float v = acc[mi][ni][r];
                h1[gm * D + gn] = f2bf(v > 0.f ? v : 0.f);
            }
}

// ---- layer-2 build: X2[b] = [ h1[b] | mean_k h1[B + b*K2 + k] ] (bf16) ----
__global__ __launch_bounds__(256)
void agg2_kernel(const unsigned short* __restrict__ h1,
                 unsigned short* __restrict__ X2) {
    const int wave = threadIdx.x >> 6;
    const int lane = threadIdx.x & 63;
    const int b = (blockIdx.x << 2) + wave;
    const ushort4 s = *(const ushort4*)(h1 + (size_t)b * D + (lane << 2));
    float sx = 0.f, sy = 0.f, sz = 0.f, sw = 0.f;
    #pragma unroll
    for (int k = 0; k < K2; ++k) {
        const ushort4 v = *(const ushort4*)(h1 + (size_t)(B_SZ + b * K2 + k) * D + (lane << 2));
        sx += bf2f(v.x); sy += bf2f(v.y); sz += bf2f(v.z); sw += bf2f(v.w);
    }
    const float inv = 1.0f / (float)K2;
    unsigned short* xr = X2 + (size_t)b * K_DIM;
    *(ushort4*)(xr + (lane << 2)) = s;
    *(ushort4*)(xr + D + (lane << 2)) =
        make_ushort4(f2bf(sx * inv), f2bf(sy * inv), f2bf(sz * inv), f2bf(sw * inv));
}

// ---- C[M,256] = relu(A[M,512] @ W[256,512]^T), m97-style K-loop (layer 2) ----
template<bool OUT_BF16>
__global__ __launch_bounds__(256)
void gemm_relu(const unsigned short* __restrict__ A,
               const unsigned short* __restrict__ W,
               void* __restrict__ Cout) {
    __shared__ unsigned short As[128 * 64];
    __shared__ unsigned short Bs[128 * 64];
    const int tid  = threadIdx.x;
    const int w    = tid >> 6, lane = tid & 63;
    const int quad = lane >> 4, l16 = lane & 15;
    const int wm = (w >> 1) << 6;
    const int wn = (w & 1) << 6;
    const size_t row0 = (size_t)blockIdx.x * 128;
    const size_t col0 = (size_t)blockIdx.y * 128;

    const int srow   = (w << 5) + (lane >> 3);
    const int schunk = ((lane & 7) ^ (lane >> 3)) << 3;
    const unsigned short* aG = A + (row0 + srow) * K_DIM + schunk;
    const unsigned short* bG = W + (col0 + srow) * K_DIM + schunk;

    f32x4 acc[4][4];
    #pragma unroll
    for (int i = 0; i < 4; ++i)
        #pragma unroll
        for (int j = 0; j < 4; ++j)
            acc[i][j] = (f32x4){0.f, 0.f, 0.f, 0.f};

    for (int k0 = 0; k0 < K_DIM; k0 += 64) {
        __syncthreads();
        #pragma unroll
        for (int n = 0; n < 4; ++n) {
            __builtin_amdgcn_global_load_lds(
                (const __attribute__((address_space(1))) void*)(aG + (size_t)(n * 8) * K_DIM + k0),
                (__attribute__((address_space(3))) void*)(As + ((w << 2) + n) * 512),
                16, 0, 0);
            __builtin_amdgcn_global_load_lds(
                (const __attribute__((address_space(1))) void*)(bG + (size_t)(n * 8) * K_DIM + k0),
                (__attribute__((address_space(3))) void*)(Bs + ((w << 2) + n) * 512),
                16, 0, 0);
        }
        __syncthreads();
        #pragma unroll
        for (int ks = 0; ks < 2; ++ks) {
            bf16x8 af[4], bfr[4];
            #pragma unroll
            for (int i = 0; i < 4; ++i) {
                const int row = wm + i * 16 + l16;
                af[i] = *(const bf16x8*)&As[row * 64 + ((((ks << 2) + quad) ^ (l16 & 7)) << 3)];
            }
            #pragma unroll
            for (int i = 0; i < 4; ++i) {
                const int row = wn + i * 16 + l16;
                bfr[i] = *(const bf16x8*)&Bs[row * 64 + ((((ks << 2) + quad) ^ (l16 & 7)) << 3)];
            }
            #pragma unroll
            for (int mi = 0; mi < 4; ++mi)
                #pragma unroll
                for (int ni = 0; ni < 4; ++ni)
                    acc[mi][ni] = __builtin_amdgcn_mfma_f32_16x16x32_bf16(
                        af[mi], bfr[ni], acc[mi][ni], 0, 0, 0);
        }
    }

    #pragma unroll
    for (int mi = 0; mi < 4; ++mi) {
        #pragma unroll
        for (int ni = 0; ni < 4; ++ni) {
            #pragma unroll
            for (int r = 0; r < 4; ++r) {
                const size_t gm = row0 + wm + mi * 16 + quad * 4 + r;
                const size_t gn = col0 + wn + ni * 16 + l16;
                float v = acc[mi][ni][r];
                v = v > 0.f ? v : 0.f;
                if (OUT_BF16)
                    ((unsigned short*)Cout)[gm * D + gn] = f2bf(v);
                else
                    ((float*)Cout)[gm * D + gn] = v;
            }
        }
    }
}

extern "C" void kernel_launch(void* const* d_in, const int* in_sizes, int n_in,
                              void* d_out, int out_size, void* d_ws, size_t ws_size,
                              hipStream_t stream) {
    const float* feat        = (const float*)d_in[0];
    const float* W1          = (const float*)d_in[1];
    const float* W2          = (const float*)d_in[2];
    const int*   nodes_batch = (const int*)d_in[3];
    const int*   neigh2      = (const int*)d_in[4];
    const int*   neigh1      = (const int*)d_in[5];
    float* out = (float*)d_out;

    char* ws = (char*)d_ws;
    unsigned*       f8   = (unsigned*)(ws);                              // 51,200,000 B
    unsigned short* h1   = (unsigned short*)(ws + 51200000);             // 23,068,672 B
    unsigned short* X2   = (unsigned short*)(ws + 51200000 + 23068672);  // 4,194,304 B
    unsigned short* W1b  = (unsigned short*)(ws + 51200000 + 23068672 + 4194304);
    unsigned short* W2b  = (unsigned short*)(ws + 51200000 + 23068672 + 4194304 + 262144);

    convert_fp8<<<25000, 256, 0, stream>>>(feat, f8);
    convert_w<<<512, 256, 0, stream>>>(W1, W2, W1b, W2b);
    fused_l1<<<M_L1 / 64, 256, 0, stream>>>(feat, f8, nodes_batch, neigh2, neigh1, W1b, h1);
    agg2_kernel<<<B_SZ / 4, 256, 0, stream>>>(h1, X2);
    gemm_relu<false><<<dim3(B_SZ / 128, 2), 256, 0, stream>>>(X2, W2b, out);
}